// Round 1
// 780.351 us; speedup vs baseline: 1.0531x; 1.0531x over previous
//
#include <hip/hip_runtime.h>
#include <stdint.h>

#define BN_EPS 0.001f

typedef float v2f __attribute__((ext_vector_type(2)));

// ---------------------------------------------------------------------------
// R10: FUSED producer-consumer kernel. fps (blocks 0..7, one per XCD-CU0) is
// the byte-identical R4 loop split into 32 chunks of 32 iterations; each chunk
// flushes its 32 centroids to new_xyz and release-publishes a per-batch
// progress counter (agent scope -> buffer_wbl2, cross-XCD visible). 248
// worker blocks (one per remaining CU) consume groups of 4 centroids in
// ready-order, running the verbatim ballq + 4-centroid MLP as soon as their
// centroids exist — overlapping ~250us of downstream work under fps's 571us
// serial chain. Blocks 256..263 (breadth-first dispatch pairs them onto the
// fps CUs) sleep until the final publish and only handle the last 16 groups,
// keeping VALU contention off the fps critical path. All FP math verbatim
// from R9 -> bit-identical outputs.
// ---------------------------------------------------------------------------

struct FpsSh {
  float px[4096], py[4096], pz[4096];
  unsigned long long wk[2][4];   // double-buffered wave winners
  int curh[32];                  // current chunk's centroid history
};

struct WrkSh {
  float W0s[67 * 64];            // 16.75 KB
  float W1s[64 * 64];            // 16 KB
  float sh[64 * 36];             // union: inT (67x34) / h1T (64x36)
  float h0T[64 * 34];            // also pmax in epilogue
  float s0c[64], t0c[64], s1c[64], t1c[64], s2c[128], t2c[128];
  float idxs[4 * 32];            // ballq results for the 4 centroids
  float cent[4 * 3];             // centroid coords for the 4 centroids
};

union AllSh {  // 54,064 B -> 2 blocks/CU guaranteed (<= 80 KB)
  FpsSh f;
  WrkSh w;
};

__global__ __launch_bounds__(256) void fused_kernel(
    const float* __restrict__ xyz, const float* __restrict__ points,
    const float* __restrict__ W0, const float* __restrict__ g0,
    const float* __restrict__ b0, const float* __restrict__ m0,
    const float* __restrict__ v0, const float* __restrict__ W1,
    const float* __restrict__ g1, const float* __restrict__ b1,
    const float* __restrict__ m1, const float* __restrict__ v1,
    const float* __restrict__ W2, const float* __restrict__ g2,
    const float* __restrict__ b2, const float* __restrict__ m2,
    const float* __restrict__ v2, float* __restrict__ new_xyz,
    float* __restrict__ new_points, float* __restrict__ idxf,
    unsigned int* __restrict__ prog) {
  __shared__ __align__(16) AllSh smem;
  const int bid = blockIdx.x;
  const int t = threadIdx.x;

  if (bid < 8) {
    // ================= FPS producer (R4 inner loop, untouched) =============
#pragma clang fp contract(off)
    float* px = smem.f.px;
    float* py = smem.f.py;
    float* pz = smem.f.pz;
    int* curh = smem.f.curh;
    auto& wk = smem.f.wk;
    const int lane = t & 63, wid = t >> 6;
    const int b = bid;
    const float* X = xyz + (size_t)b * 4096 * 3;
    float* out = new_xyz + (size_t)b * 1024 * 3;
    v2f x[8], y[8], z[8], dist[8];
#pragma unroll
    for (int j = 0; j < 8; ++j) {
      const int n0 = (2 * j) * 256 + t;
      const int n1 = (2 * j + 1) * 256 + t;
      x[j].x = X[n0 * 3 + 0]; x[j].y = X[n1 * 3 + 0];
      y[j].x = X[n0 * 3 + 1]; y[j].y = X[n1 * 3 + 1];
      z[j].x = X[n0 * 3 + 2]; z[j].y = X[n1 * 3 + 2];
      px[n0] = x[j].x; py[n0] = y[j].x; pz[n0] = z[j].x;
      px[n1] = x[j].y; py[n1] = y[j].y; pz[n1] = z[j].y;
      dist[j] = (v2f){1e10f, 1e10f};
    }
    __syncthreads();
    int cur = 0;
    for (int cc = 0; cc < 32; ++cc) {
      for (int ii = 0; ii < 32; ++ii) {
        const int it = cc * 32 + ii;
        if (t == 0) curh[ii] = cur;        // LDS only: no vmcnt on the barrier
        const float cx = px[cur], cy = py[cur], cz = pz[cur];
        const v2f cxv = {cx, cx}, cyv = {cy, cy}, czv = {cz, cz};
        float bestv = -1.0f;
        int bestj = 0;
#pragma unroll
        for (int j = 0; j < 8; ++j) {
          v2f dx = x[j] - cxv, dy = y[j] - cyv, dz = z[j] - czv;
          v2f d = dx * dx + dy * dy;   // contract off: mul,mul,add — matches ref
          d = d + dz * dz;
          v2f nd = __builtin_elementwise_min(dist[j], d);
          dist[j] = nd;
          if (nd.x > bestv) { bestv = nd.x; bestj = 2 * j; }      // strict >
          if (nd.y > bestv) { bestv = nd.y; bestj = 2 * j + 1; }
        }
        const int besti = bestj * 256 + t;
        unsigned long long key =
            ((unsigned long long)__float_as_uint(bestv) << 32) | (unsigned)(~besti);
        // ---- wave64 max-reduce via DPP; result lands in lane 63 ----
#define DPP_STEP(CTRL)                                                                     \
        {                                                                                  \
          unsigned lo_ = (unsigned)key, hi_ = (unsigned)(key >> 32);                       \
          unsigned ls = (unsigned)__builtin_amdgcn_update_dpp((int)lo_, (int)lo_, CTRL, 0xf, 0xf, false); \
          unsigned hs = (unsigned)__builtin_amdgcn_update_dpp((int)hi_, (int)hi_, CTRL, 0xf, 0xf, false); \
          unsigned long long sk = ((unsigned long long)hs << 32) | ls;                     \
          if (sk > key) key = sk;                                                          \
        }
        DPP_STEP(0x111)  // row_shr:1
        DPP_STEP(0x112)  // row_shr:2
        DPP_STEP(0x114)  // row_shr:4
        DPP_STEP(0x118)  // row_shr:8
        DPP_STEP(0x142)  // row_bcast:15
        DPP_STEP(0x143)  // row_bcast:31
#undef DPP_STEP
        const unsigned whi = (unsigned)__builtin_amdgcn_readlane((int)(key >> 32), 63);
        const unsigned wlo = (unsigned)__builtin_amdgcn_readlane((int)key, 63);
        if (lane == 0) wk[it & 1][wid] = ((unsigned long long)whi << 32) | wlo;
        __syncthreads();
        const unsigned long long k0 = wk[it & 1][0], k1 = wk[it & 1][1];
        const unsigned long long k2 = wk[it & 1][2], k3 = wk[it & 1][3];
        unsigned long long b01 = (k1 > k0) ? k1 : k0;
        unsigned long long b23 = (k3 > k2) ? k3 : k2;
        unsigned long long bk = (b23 > b01) ? b23 : b01;
        cur = (int)(~(unsigned)(bk & 0xffffffffull));
      }
      // ---- chunk flush: store 32 centroids, then release-publish progress ----
      if (t < 32) {
        const int c = curh[t];
        const int p = cc * 32 + t;
        out[p * 3 + 0] = px[c];
        out[p * 3 + 1] = py[c];
        out[p * 3 + 2] = pz[c];
      }
      __syncthreads();  // compiler-emitted vmcnt(0) drains the 96 stores
      if (t == 0)
        __hip_atomic_store(&prog[b * 32], (unsigned)(cc * 32 + 32),
                           __ATOMIC_RELEASE, __HIP_MEMORY_SCOPE_AGENT);
    }
    return;
  }

  // ================= worker: ballq + MLP per group of 4 centroids ==========
  float* W0s = smem.w.W0s;
  float* W1s = smem.w.W1s;
  float* s0c = smem.w.s0c; float* t0c = smem.w.t0c;
  float* s1c = smem.w.s1c; float* t1c = smem.w.t1c;
  float* s2c = smem.w.s2c; float* t2c = smem.w.t2c;
  for (int i = t; i < 67 * 64; i += 256) W0s[i] = W0[i];
  for (int i = t; i < 64 * 64; i += 256) W1s[i] = W1[i];
  if (t < 64) {
    float s = g0[t] * rsqrtf(v0[t] + BN_EPS); s0c[t] = s; t0c[t] = b0[t] - m0[t] * s;
    float u = g1[t] * rsqrtf(v1[t] + BN_EPS); s1c[t] = u; t1c[t] = b1[t] - m1[t] * u;
  }
  if (t < 128) {
    float s = g2[t] * rsqrtf(v2[t] + BN_EPS); s2c[t] = s; t2c[t] = b2[t] - m2[t] * s;
  }
  __syncthreads();
  const int sgrp = t & 15, dgrp = t >> 4;  // L0/L1 tiling
  const int dg2 = t & 31, sg2 = t >> 5;    // L2 tiling
  float* inT = smem.w.sh;                  // [c][s] stride 34, gather..L0
  float* h1T = smem.w.sh;                  // [d][s] stride 36, L1..L2
  float* h0T = smem.w.h0T;
  float* pmax = h0T;                       // alias (h0T dead by L2 epilogue)

  // Group schedule in ready-order k = j*8 + b (j = local group, b = batch).
  // Normals (bid 8..255): k = w, w+248, ... over [0, 2032).
  // Tails (bid 256..263, co-resident with fps CUs): sleep till the end,
  // then k = 2032+w and 2040+w.
  int kbeg, kend, kstep;
  if (bid >= 256) { kbeg = 2032 + (bid - 256); kend = 2048; kstep = 8; }
  else            { kbeg = bid - 8;            kend = 2032; kstep = 248; }

  for (int k = kbeg; k < kend; k += kstep) {
    const int j = k >> 3, b = k & 7;
    const int pgbase = b * 1024 + j * 4;
    const unsigned need = (unsigned)(j * 4 + 4);
    {
      int guard = 0;
      while (__hip_atomic_load(&prog[b * 32], __ATOMIC_RELAXED,
                               __HIP_MEMORY_SCOPE_AGENT) < need) {
        __builtin_amdgcn_s_sleep(32);
        if (++guard > (1 << 20)) break;   // failsafe: never hang the harness
      }
      // acquire fence: invalidate stale L1/L2 lines before consuming coords
      (void)__hip_atomic_load(&prog[b * 32], __ATOMIC_ACQUIRE,
                              __HIP_MEMORY_SCOPE_AGENT);
    }
    // ---- ball query: wave wv handles centroid pgbase+wv (verbatim math) ----
    {
#pragma clang fp contract(off)
      const int wv = t >> 6, lane = t & 63;
      const int pg = pgbase + wv;
      const float* X = xyz + (size_t)b * 4096 * 3;
      const float cx = new_xyz[pg * 3 + 0];
      const float cy = new_xyz[pg * 3 + 1];
      const float cz = new_xyz[pg * 3 + 2];
      const float csq = (cx * cx + cy * cy) + cz * cz;
      float* outg = idxf + (size_t)pg * 32;
      float* ol = smem.w.idxs + wv * 32;
      int total = 0;
      int first = -1;
      for (int chunk = 0; chunk < 64; ++chunk) {
        const int n = chunk * 64 + lane;
        const float xx = X[n * 3 + 0], yy = X[n * 3 + 1], zz = X[n * 3 + 2];
        const float sq = (xx * xx + yy * yy) + zz * zz;
        const float dot = fmaf(cz, zz, fmaf(cy, yy, cx * xx));  // gemm K-chain
        const float d2 = (csq + sq) - 2.0f * dot;
        const bool in = d2 < 0.04f;
        const unsigned long long mask = __ballot(in);
        if (first < 0 && mask != 0ull) first = chunk * 64 + __builtin_ctzll(mask);
        if (in) {
          const int pos = total + __builtin_popcountll(mask & ((1ull << lane) - 1ull));
          if (pos < 32) { outg[pos] = (float)n; ol[pos] = (float)n; }
        }
        total += __builtin_popcountll(mask);
        if (total >= 32) break;
      }
      if (total < 32 && first >= 0) {
        const int slot = total + lane;
        if (slot < 32) { outg[slot] = (float)first; ol[slot] = (float)first; }
      }
      if (lane == 0) {
        smem.w.cent[wv * 3 + 0] = cx;
        smem.w.cent[wv * 3 + 1] = cy;
        smem.w.cent[wv * 3 + 2] = cz;
      }
    }
    __syncthreads();
    // ---- MLP: 4 centroids sequentially (verbatim R9 math) ----
    for (int pp = 0; pp < 4; ++pp) {
      const int pg = pgbase + pp;
      const float cx = smem.w.cent[pp * 3 + 0];
      const float cy = smem.w.cent[pp * 3 + 1];
      const float cz = smem.w.cent[pp * 3 + 2];
      // ---- gather stage (writes inT) ----
      {
        const int s = t >> 3, cg = t & 7;
        const int i = (int)smem.w.idxs[pp * 32 + s];
        const float* Pr = points + ((size_t)b * 4096 + i) * 64 + cg * 8;
        const float4 a = *(const float4*)Pr;
        const float4 c4 = *(const float4*)(Pr + 4);
        const int r = 3 + cg * 8;
        inT[(r + 0) * 34 + s] = a.x;  inT[(r + 1) * 34 + s] = a.y;
        inT[(r + 2) * 34 + s] = a.z;  inT[(r + 3) * 34 + s] = a.w;
        inT[(r + 4) * 34 + s] = c4.x; inT[(r + 5) * 34 + s] = c4.y;
        inT[(r + 6) * 34 + s] = c4.z; inT[(r + 7) * 34 + s] = c4.w;
        if (t < 32) {
          const int i2 = (int)smem.w.idxs[pp * 32 + t];
          const float* Xr = xyz + ((size_t)b * 4096 + i2) * 3;
          inT[0 * 34 + t] = Xr[0] - cx;
          inT[1 * 34 + t] = Xr[1] - cy;
          inT[2 * 34 + t] = Xr[2] - cz;
        }
      }
      __syncthreads();
      // ---- L0: 67 -> 64 ----
      {
        float acc[2][4] = {{0, 0, 0, 0}, {0, 0, 0, 0}};
#pragma unroll 4
        for (int c = 0; c < 67; ++c) {
          const float2 a = *(const float2*)&inT[c * 34 + 2 * sgrp];
          const float4 w = *(const float4*)&W0s[c * 64 + 4 * dgrp];
          acc[0][0] = fmaf(a.x, w.x, acc[0][0]); acc[0][1] = fmaf(a.x, w.y, acc[0][1]);
          acc[0][2] = fmaf(a.x, w.z, acc[0][2]); acc[0][3] = fmaf(a.x, w.w, acc[0][3]);
          acc[1][0] = fmaf(a.y, w.x, acc[1][0]); acc[1][1] = fmaf(a.y, w.y, acc[1][1]);
          acc[1][2] = fmaf(a.y, w.z, acc[1][2]); acc[1][3] = fmaf(a.y, w.w, acc[1][3]);
        }
#pragma unroll
        for (int dj = 0; dj < 4; ++dj) {
          const int d = 4 * dgrp + dj;
          const float s = s0c[d], bb = t0c[d];
#pragma unroll
          for (int si = 0; si < 2; ++si) {
            float yv = fmaf(acc[si][dj], s, bb);
            h0T[d * 34 + 2 * sgrp + si] = fmaxf(yv, 0.0f);
          }
        }
      }
      __syncthreads();
      // ---- L1: 64 -> 64 ----
      {
        float acc[2][4] = {{0, 0, 0, 0}, {0, 0, 0, 0}};
#pragma unroll 4
        for (int c = 0; c < 64; ++c) {
          const float2 a = *(const float2*)&h0T[c * 34 + 2 * sgrp];
          const float4 w = *(const float4*)&W1s[c * 64 + 4 * dgrp];
          acc[0][0] = fmaf(a.x, w.x, acc[0][0]); acc[0][1] = fmaf(a.x, w.y, acc[0][1]);
          acc[0][2] = fmaf(a.x, w.z, acc[0][2]); acc[0][3] = fmaf(a.x, w.w, acc[0][3]);
          acc[1][0] = fmaf(a.y, w.x, acc[1][0]); acc[1][1] = fmaf(a.y, w.y, acc[1][1]);
          acc[1][2] = fmaf(a.y, w.z, acc[1][2]); acc[1][3] = fmaf(a.y, w.w, acc[1][3]);
        }
#pragma unroll
        for (int dj = 0; dj < 4; ++dj) {
          const int d = 4 * dgrp + dj;
          const float s = s1c[d], bb = t1c[d];
#pragma unroll
          for (int si = 0; si < 2; ++si) {
            float yv = fmaf(acc[si][dj], s, bb);
            h1T[d * 36 + 2 * sgrp + si] = fmaxf(yv, 0.0f);
          }
        }
      }
      __syncthreads();
      // ---- L2: 64 -> 128, fused BN+ReLU+max ----
      {
        float acc[4][4] = {{0,0,0,0},{0,0,0,0},{0,0,0,0},{0,0,0,0}};
#pragma unroll 8
        for (int c = 0; c < 64; ++c) {
          const float4 a = *(const float4*)&h1T[c * 36 + 4 * sg2];
          const float4 w = *(const float4*)(W2 + c * 128 + 4 * dg2);
          acc[0][0] = fmaf(a.x, w.x, acc[0][0]); acc[0][1] = fmaf(a.x, w.y, acc[0][1]);
          acc[0][2] = fmaf(a.x, w.z, acc[0][2]); acc[0][3] = fmaf(a.x, w.w, acc[0][3]);
          acc[1][0] = fmaf(a.y, w.x, acc[1][0]); acc[1][1] = fmaf(a.y, w.y, acc[1][1]);
          acc[1][2] = fmaf(a.y, w.z, acc[1][2]); acc[1][3] = fmaf(a.y, w.w, acc[1][3]);
          acc[2][0] = fmaf(a.z, w.x, acc[2][0]); acc[2][1] = fmaf(a.z, w.y, acc[2][1]);
          acc[2][2] = fmaf(a.z, w.z, acc[2][2]); acc[2][3] = fmaf(a.z, w.w, acc[2][3]);
          acc[3][0] = fmaf(a.w, w.x, acc[3][0]); acc[3][1] = fmaf(a.w, w.y, acc[3][1]);
          acc[3][2] = fmaf(a.w, w.z, acc[3][2]); acc[3][3] = fmaf(a.w, w.w, acc[3][3]);
        }
#pragma unroll
        for (int dj = 0; dj < 4; ++dj) {
          const int d = 4 * dg2 + dj;
          const float s = s2c[d], bb = t2c[d];
          float mx = 0.0f;  // relu outputs are >= 0
#pragma unroll
          for (int si = 0; si < 4; ++si) {
            float yv = fmaf(acc[si][dj], s, bb);
            mx = fmaxf(mx, fmaxf(yv, 0.0f));
          }
          pmax[sg2 * 128 + d] = mx;
        }
      }
      __syncthreads();
      if (t < 128) {
        float mx = pmax[t];
#pragma unroll
        for (int g = 1; g < 8; ++g) mx = fmaxf(mx, pmax[g * 128 + t]);
        new_points[(size_t)pg * 128 + t] = mx;
      }
      __syncthreads();
    }
  }
}

extern "C" void kernel_launch(void* const* d_in, const int* in_sizes, int n_in,
                              void* d_out, int out_size, void* d_ws, size_t ws_size,
                              hipStream_t stream) {
  (void)in_sizes; (void)n_in; (void)out_size; (void)ws_size;
  const float* xyz    = (const float*)d_in[0];
  const float* points = (const float*)d_in[1];
  const float* W0 = (const float*)d_in[2];
  const float* g0 = (const float*)d_in[3];
  const float* b0 = (const float*)d_in[4];
  const float* m0 = (const float*)d_in[5];
  const float* v0 = (const float*)d_in[6];
  const float* W1 = (const float*)d_in[7];
  const float* g1 = (const float*)d_in[8];
  const float* b1 = (const float*)d_in[9];
  const float* m1 = (const float*)d_in[10];
  const float* v1 = (const float*)d_in[11];
  const float* W2 = (const float*)d_in[12];
  const float* g2 = (const float*)d_in[13];
  const float* b2 = (const float*)d_in[14];
  const float* m2 = (const float*)d_in[15];
  const float* v2 = (const float*)d_in[16];

  float* new_xyz    = (float*)d_out;                 // 8*1024*3
  float* new_points = new_xyz + 8 * 1024 * 3;        // 8*1024*128
  float* idxf       = new_points + 8 * 1024 * 128;   // 8*1024*32

  unsigned int* prog = (unsigned int*)d_ws;          // 8 counters, 128B apart
  hipMemsetAsync(d_ws, 0, 8 * 32 * sizeof(unsigned int), stream);
  fused_kernel<<<264, 256, 0, stream>>>(xyz, points, W0, g0, b0, m0, v0,
                                        W1, g1, b1, m1, v1,
                                        W2, g2, b2, m2, v2,
                                        new_xyz, new_points, idxf, prog);
}

// Round 2
// 744.417 us; speedup vs baseline: 1.1040x; 1.0483x over previous
//
#include <hip/hip_runtime.h>
#include <stdint.h>

#define BN_EPS 0.001f

typedef float v2f __attribute__((ext_vector_type(2)));

// ---------------------------------------------------------------------------
// R11: fused producer-consumer, RELAXED-ATOMIC protocol (no wbl2/inv).
// R10 lesson: RELEASE/ACQUIRE at agent scope emit buffer_wbl2 / buffer_inv —
// full-L2 writeback on fps's critical path (32x) and full-L2 invalidate per
// worker group (~2048x), costing ~100us (cold W2/points/xyz in the tail) and
// causing a 31.8ms latency-spike dispatch. The ONLY cross-block data are
// prog and new_xyz -> move both to agent-scope RELAXED atomics (sc1: bypass
// non-coherent L2s, coherent at MALL; no cache maintenance). Ordering
// data->flag via s_waitcnt vmcnt(0) (sc1 stores are device-visible once
// vmcnt drains). Read-only inputs (xyz/points/W*) keep normal cached loads —
// L2 stays warm across groups now.
// Tail reshape: centroids 1016..1023 x 8 batches (ready only at the FINAL
// publish) go to 64 single-centroid sleeper blocks (was 8 blocks x 8
// centroids) -> tail ~= one 1-centroid pipeline (~10us) instead of ~90us.
// All FP math verbatim from R9/R10 -> bit-identical outputs.
// ---------------------------------------------------------------------------

struct FpsSh {
  float px[4096], py[4096], pz[4096];
  unsigned long long wk[2][4];   // double-buffered wave winners
  int curh[32];                  // current chunk's centroid history
};

struct WrkSh {
  float W0s[67 * 64];            // 16.75 KB
  float W1s[64 * 64];            // 16 KB
  float sh[64 * 36];             // union: inT (67x34) / h1T (64x36)
  float h0T[64 * 34];            // also pmax in epilogue
  float s0c[64], t0c[64], s1c[64], t1c[64], s2c[128], t2c[128];
  float idxs[4 * 32];            // ballq results for up to 4 centroids
  float cent[4 * 3];             // centroid coords
};

union AllSh {  // 54,064 B -> 3 blocks/CU by LDS; grid 320 fully co-resident
  FpsSh f;
  WrkSh w;
};

__global__ __launch_bounds__(256) void fused_kernel(
    const float* __restrict__ xyz, const float* __restrict__ points,
    const float* __restrict__ W0, const float* __restrict__ g0,
    const float* __restrict__ b0, const float* __restrict__ m0,
    const float* __restrict__ v0, const float* __restrict__ W1,
    const float* __restrict__ g1, const float* __restrict__ b1,
    const float* __restrict__ m1, const float* __restrict__ v1,
    const float* __restrict__ W2, const float* __restrict__ g2,
    const float* __restrict__ b2, const float* __restrict__ m2,
    const float* __restrict__ v2, float* __restrict__ new_xyz,
    float* __restrict__ new_points, float* __restrict__ idxf,
    unsigned int* __restrict__ prog) {
  __shared__ __align__(16) AllSh smem;
  const int bid = blockIdx.x;
  const int t = threadIdx.x;

  if (bid < 8) {
    // ================= FPS producer (R4 inner loop, untouched) =============
#pragma clang fp contract(off)
    float* px = smem.f.px;
    float* py = smem.f.py;
    float* pz = smem.f.pz;
    int* curh = smem.f.curh;
    auto& wk = smem.f.wk;
    const int lane = t & 63, wid = t >> 6;
    const int b = bid;
    const float* X = xyz + (size_t)b * 4096 * 3;
    float* out = new_xyz + (size_t)b * 1024 * 3;
    v2f x[8], y[8], z[8], dist[8];
#pragma unroll
    for (int j = 0; j < 8; ++j) {
      const int n0 = (2 * j) * 256 + t;
      const int n1 = (2 * j + 1) * 256 + t;
      x[j].x = X[n0 * 3 + 0]; x[j].y = X[n1 * 3 + 0];
      y[j].x = X[n0 * 3 + 1]; y[j].y = X[n1 * 3 + 1];
      z[j].x = X[n0 * 3 + 2]; z[j].y = X[n1 * 3 + 2];
      px[n0] = x[j].x; py[n0] = y[j].x; pz[n0] = z[j].x;
      px[n1] = x[j].y; py[n1] = y[j].y; pz[n1] = z[j].y;
      dist[j] = (v2f){1e10f, 1e10f};
    }
    __syncthreads();
    int cur = 0;
    for (int cc = 0; cc < 32; ++cc) {
      for (int ii = 0; ii < 32; ++ii) {
        const int it = cc * 32 + ii;
        if (t == 0) curh[ii] = cur;        // LDS only: no vmcnt on the barrier
        const float cx = px[cur], cy = py[cur], cz = pz[cur];
        const v2f cxv = {cx, cx}, cyv = {cy, cy}, czv = {cz, cz};
        float bestv = -1.0f;
        int bestj = 0;
#pragma unroll
        for (int j = 0; j < 8; ++j) {
          v2f dx = x[j] - cxv, dy = y[j] - cyv, dz = z[j] - czv;
          v2f d = dx * dx + dy * dy;   // contract off: mul,mul,add — matches ref
          d = d + dz * dz;
          v2f nd = __builtin_elementwise_min(dist[j], d);
          dist[j] = nd;
          if (nd.x > bestv) { bestv = nd.x; bestj = 2 * j; }      // strict >
          if (nd.y > bestv) { bestv = nd.y; bestj = 2 * j + 1; }
        }
        const int besti = bestj * 256 + t;
        unsigned long long key =
            ((unsigned long long)__float_as_uint(bestv) << 32) | (unsigned)(~besti);
        // ---- wave64 max-reduce via DPP; result lands in lane 63 ----
#define DPP_STEP(CTRL)                                                                     \
        {                                                                                  \
          unsigned lo_ = (unsigned)key, hi_ = (unsigned)(key >> 32);                       \
          unsigned ls = (unsigned)__builtin_amdgcn_update_dpp((int)lo_, (int)lo_, CTRL, 0xf, 0xf, false); \
          unsigned hs = (unsigned)__builtin_amdgcn_update_dpp((int)hi_, (int)hi_, CTRL, 0xf, 0xf, false); \
          unsigned long long sk = ((unsigned long long)hs << 32) | ls;                     \
          if (sk > key) key = sk;                                                          \
        }
        DPP_STEP(0x111)  // row_shr:1
        DPP_STEP(0x112)  // row_shr:2
        DPP_STEP(0x114)  // row_shr:4
        DPP_STEP(0x118)  // row_shr:8
        DPP_STEP(0x142)  // row_bcast:15
        DPP_STEP(0x143)  // row_bcast:31
#undef DPP_STEP
        const unsigned whi = (unsigned)__builtin_amdgcn_readlane((int)(key >> 32), 63);
        const unsigned wlo = (unsigned)__builtin_amdgcn_readlane((int)key, 63);
        if (lane == 0) wk[it & 1][wid] = ((unsigned long long)whi << 32) | wlo;
        __syncthreads();
        const unsigned long long k0 = wk[it & 1][0], k1 = wk[it & 1][1];
        const unsigned long long k2 = wk[it & 1][2], k3 = wk[it & 1][3];
        unsigned long long b01 = (k1 > k0) ? k1 : k0;
        unsigned long long b23 = (k3 > k2) ? k3 : k2;
        unsigned long long bk = (b23 > b01) ? b23 : b01;
        cur = (int)(~(unsigned)(bk & 0xffffffffull));
      }
      // ---- chunk flush: sc1 data stores, vmcnt drain, relaxed publish ----
      if (t < 32) {
        const int c = curh[t];
        const int p = cc * 32 + t;
        __hip_atomic_store(&out[p * 3 + 0], px[c], __ATOMIC_RELAXED,
                           __HIP_MEMORY_SCOPE_AGENT);
        __hip_atomic_store(&out[p * 3 + 1], py[c], __ATOMIC_RELAXED,
                           __HIP_MEMORY_SCOPE_AGENT);
        __hip_atomic_store(&out[p * 3 + 2], pz[c], __ATOMIC_RELAXED,
                           __HIP_MEMORY_SCOPE_AGENT);
      }
      __syncthreads();  // wave0's vmcnt(0) drain orders data ahead of flag
      if (t == 0) {
        asm volatile("s_waitcnt vmcnt(0)" ::: "memory");
        __hip_atomic_store(&prog[b * 32], (unsigned)(cc * 32 + 32),
                           __ATOMIC_RELAXED, __HIP_MEMORY_SCOPE_AGENT);
      }
    }
    return;
  }

  // ================= worker: ballq + MLP =================================
  float* W0s = smem.w.W0s;
  float* W1s = smem.w.W1s;
  float* s0c = smem.w.s0c; float* t0c = smem.w.t0c;
  float* s1c = smem.w.s1c; float* t1c = smem.w.t1c;
  float* s2c = smem.w.s2c; float* t2c = smem.w.t2c;
  for (int i = t; i < 67 * 64; i += 256) W0s[i] = W0[i];
  for (int i = t; i < 64 * 64; i += 256) W1s[i] = W1[i];
  if (t < 64) {
    float s = g0[t] * rsqrtf(v0[t] + BN_EPS); s0c[t] = s; t0c[t] = b0[t] - m0[t] * s;
    float u = g1[t] * rsqrtf(v1[t] + BN_EPS); s1c[t] = u; t1c[t] = b1[t] - m1[t] * u;
  }
  if (t < 128) {
    float s = g2[t] * rsqrtf(v2[t] + BN_EPS); s2c[t] = s; t2c[t] = b2[t] - m2[t] * s;
  }
  __syncthreads();
  const int sgrp = t & 15, dgrp = t >> 4;  // L0/L1 tiling
  const int dg2 = t & 31, sg2 = t >> 5;    // L2 tiling
  float* inT = smem.w.sh;                  // [c][s] stride 34, gather..L0
  float* h1T = smem.w.sh;                  // [d][s] stride 36, L1..L2
  float* h0T = smem.w.h0T;
  float* pmax = h0T;                       // alias (h0T dead by L2 epilogue)

  // Spin-wait on per-batch progress (relaxed agent loads: sc1, always fresh,
  // NO cache invalidation). Failsafe bounds any hang; legit waits are <600
  // polls (~1.1us each), guard is ~1e6.
  auto wait_prog = [&](int b, unsigned need) {
    int guard = 0;
    while (__hip_atomic_load(&prog[b * 32], __ATOMIC_RELAXED,
                             __HIP_MEMORY_SCOPE_AGENT) < need) {
      __builtin_amdgcn_s_sleep(32);
      if (++guard > (1 << 20)) break;
    }
  };

  // ballq + MLP for nc centroids starting at (batch b, point p0).
  auto process_group = [&](int b, int p0, int nc) {
    // ---- ball query: wave wv handles centroid p0+wv (verbatim math) ----
    {
#pragma clang fp contract(off)
      const int wv = t >> 6, lane = t & 63;
      if (wv < nc) {
        const int pg = b * 1024 + p0 + wv;
        const float* X = xyz + (size_t)b * 4096 * 3;
        const float cx = __hip_atomic_load(&new_xyz[pg * 3 + 0], __ATOMIC_RELAXED,
                                           __HIP_MEMORY_SCOPE_AGENT);
        const float cy = __hip_atomic_load(&new_xyz[pg * 3 + 1], __ATOMIC_RELAXED,
                                           __HIP_MEMORY_SCOPE_AGENT);
        const float cz = __hip_atomic_load(&new_xyz[pg * 3 + 2], __ATOMIC_RELAXED,
                                           __HIP_MEMORY_SCOPE_AGENT);
        const float csq = (cx * cx + cy * cy) + cz * cz;
        float* outg = idxf + (size_t)pg * 32;
        float* ol = smem.w.idxs + wv * 32;
        int total = 0;
        int first = -1;
        for (int chunk = 0; chunk < 64; ++chunk) {
          const int n = chunk * 64 + lane;
          const float xx = X[n * 3 + 0], yy = X[n * 3 + 1], zz = X[n * 3 + 2];
          const float sq = (xx * xx + yy * yy) + zz * zz;
          const float dot = fmaf(cz, zz, fmaf(cy, yy, cx * xx));  // gemm K-chain
          const float d2 = (csq + sq) - 2.0f * dot;
          const bool in = d2 < 0.04f;
          const unsigned long long mask = __ballot(in);
          if (first < 0 && mask != 0ull) first = chunk * 64 + __builtin_ctzll(mask);
          if (in) {
            const int pos = total + __builtin_popcountll(mask & ((1ull << lane) - 1ull));
            if (pos < 32) { outg[pos] = (float)n; ol[pos] = (float)n; }
          }
          total += __builtin_popcountll(mask);
          if (total >= 32) break;
        }
        if (total < 32 && first >= 0) {
          const int slot = total + lane;
          if (slot < 32) { outg[slot] = (float)first; ol[slot] = (float)first; }
        }
        if (lane == 0) {
          smem.w.cent[wv * 3 + 0] = cx;
          smem.w.cent[wv * 3 + 1] = cy;
          smem.w.cent[wv * 3 + 2] = cz;
        }
      }
    }
    __syncthreads();
    // ---- MLP: nc centroids sequentially (verbatim R9 math) ----
    for (int pp = 0; pp < nc; ++pp) {
      const int pg = b * 1024 + p0 + pp;
      const float cx = smem.w.cent[pp * 3 + 0];
      const float cy = smem.w.cent[pp * 3 + 1];
      const float cz = smem.w.cent[pp * 3 + 2];
      // ---- gather stage (writes inT) ----
      {
        const int s = t >> 3, cg = t & 7;
        const int i = (int)smem.w.idxs[pp * 32 + s];
        const float* Pr = points + ((size_t)b * 4096 + i) * 64 + cg * 8;
        const float4 a = *(const float4*)Pr;
        const float4 c4 = *(const float4*)(Pr + 4);
        const int r = 3 + cg * 8;
        inT[(r + 0) * 34 + s] = a.x;  inT[(r + 1) * 34 + s] = a.y;
        inT[(r + 2) * 34 + s] = a.z;  inT[(r + 3) * 34 + s] = a.w;
        inT[(r + 4) * 34 + s] = c4.x; inT[(r + 5) * 34 + s] = c4.y;
        inT[(r + 6) * 34 + s] = c4.z; inT[(r + 7) * 34 + s] = c4.w;
        if (t < 32) {
          const int i2 = (int)smem.w.idxs[pp * 32 + t];
          const float* Xr = xyz + ((size_t)b * 4096 + i2) * 3;
          inT[0 * 34 + t] = Xr[0] - cx;
          inT[1 * 34 + t] = Xr[1] - cy;
          inT[2 * 34 + t] = Xr[2] - cz;
        }
      }
      __syncthreads();
      // ---- L0: 67 -> 64 ----
      {
        float acc[2][4] = {{0, 0, 0, 0}, {0, 0, 0, 0}};
#pragma unroll 4
        for (int c = 0; c < 67; ++c) {
          const float2 a = *(const float2*)&inT[c * 34 + 2 * sgrp];
          const float4 w = *(const float4*)&W0s[c * 64 + 4 * dgrp];
          acc[0][0] = fmaf(a.x, w.x, acc[0][0]); acc[0][1] = fmaf(a.x, w.y, acc[0][1]);
          acc[0][2] = fmaf(a.x, w.z, acc[0][2]); acc[0][3] = fmaf(a.x, w.w, acc[0][3]);
          acc[1][0] = fmaf(a.y, w.x, acc[1][0]); acc[1][1] = fmaf(a.y, w.y, acc[1][1]);
          acc[1][2] = fmaf(a.y, w.z, acc[1][2]); acc[1][3] = fmaf(a.y, w.w, acc[1][3]);
        }
#pragma unroll
        for (int dj = 0; dj < 4; ++dj) {
          const int d = 4 * dgrp + dj;
          const float s = s0c[d], bb = t0c[d];
#pragma unroll
          for (int si = 0; si < 2; ++si) {
            float yv = fmaf(acc[si][dj], s, bb);
            h0T[d * 34 + 2 * sgrp + si] = fmaxf(yv, 0.0f);
          }
        }
      }
      __syncthreads();
      // ---- L1: 64 -> 64 ----
      {
        float acc[2][4] = {{0, 0, 0, 0}, {0, 0, 0, 0}};
#pragma unroll 4
        for (int c = 0; c < 64; ++c) {
          const float2 a = *(const float2*)&h0T[c * 34 + 2 * sgrp];
          const float4 w = *(const float4*)&W1s[c * 64 + 4 * dgrp];
          acc[0][0] = fmaf(a.x, w.x, acc[0][0]); acc[0][1] = fmaf(a.x, w.y, acc[0][1]);
          acc[0][2] = fmaf(a.x, w.z, acc[0][2]); acc[0][3] = fmaf(a.x, w.w, acc[0][3]);
          acc[1][0] = fmaf(a.y, w.x, acc[1][0]); acc[1][1] = fmaf(a.y, w.y, acc[1][1]);
          acc[1][2] = fmaf(a.y, w.z, acc[1][2]); acc[1][3] = fmaf(a.y, w.w, acc[1][3]);
        }
#pragma unroll
        for (int dj = 0; dj < 4; ++dj) {
          const int d = 4 * dgrp + dj;
          const float s = s1c[d], bb = t1c[d];
#pragma unroll
          for (int si = 0; si < 2; ++si) {
            float yv = fmaf(acc[si][dj], s, bb);
            h1T[d * 36 + 2 * sgrp + si] = fmaxf(yv, 0.0f);
          }
        }
      }
      __syncthreads();
      // ---- L2: 64 -> 128, fused BN+ReLU+max ----
      {
        float acc[4][4] = {{0,0,0,0},{0,0,0,0},{0,0,0,0},{0,0,0,0}};
#pragma unroll 8
        for (int c = 0; c < 64; ++c) {
          const float4 a = *(const float4*)&h1T[c * 36 + 4 * sg2];
          const float4 w = *(const float4*)(W2 + c * 128 + 4 * dg2);
          acc[0][0] = fmaf(a.x, w.x, acc[0][0]); acc[0][1] = fmaf(a.x, w.y, acc[0][1]);
          acc[0][2] = fmaf(a.x, w.z, acc[0][2]); acc[0][3] = fmaf(a.x, w.w, acc[0][3]);
          acc[1][0] = fmaf(a.y, w.x, acc[1][0]); acc[1][1] = fmaf(a.y, w.y, acc[1][1]);
          acc[1][2] = fmaf(a.y, w.z, acc[1][2]); acc[1][3] = fmaf(a.y, w.w, acc[1][3]);
          acc[2][0] = fmaf(a.z, w.x, acc[2][0]); acc[2][1] = fmaf(a.z, w.y, acc[2][1]);
          acc[2][2] = fmaf(a.z, w.z, acc[2][2]); acc[2][3] = fmaf(a.z, w.w, acc[2][3]);
          acc[3][0] = fmaf(a.w, w.x, acc[3][0]); acc[3][1] = fmaf(a.w, w.y, acc[3][1]);
          acc[3][2] = fmaf(a.w, w.z, acc[3][2]); acc[3][3] = fmaf(a.w, w.w, acc[3][3]);
        }
#pragma unroll
        for (int dj = 0; dj < 4; ++dj) {
          const int d = 4 * dg2 + dj;
          const float s = s2c[d], bb = t2c[d];
          float mx = 0.0f;  // relu outputs are >= 0
#pragma unroll
          for (int si = 0; si < 4; ++si) {
            float yv = fmaf(acc[si][dj], s, bb);
            mx = fmaxf(mx, fmaxf(yv, 0.0f));
          }
          pmax[sg2 * 128 + d] = mx;
        }
      }
      __syncthreads();
      if (t < 128) {
        float mx = pmax[t];
#pragma unroll
        for (int g = 1; g < 8; ++g) mx = fmaxf(mx, pmax[g * 128 + t]);
        new_points[(size_t)pg * 128 + t] = mx;
      }
      __syncthreads();
    }
  };

  if (bid >= 256) {
    // 64 single-centroid sleepers for the final-publish cliff: centroids
    // 1016..1023 of each batch become ready only when prog hits 1024.
    const int sid = bid - 256;          // 0..63
    const int b = sid & 7;              // spread across batches/XCDs
    const int p0 = 1016 + (sid >> 3);   // 1016..1023
    wait_prog(b, (unsigned)(p0 + 1));
    process_group(b, p0, 1);
  } else {
    // 248 normal workers, groups of 4 centroids in ready-order k = j*8 + b.
    for (int k = bid - 8; k < 2032; k += 248) {
      const int j = k >> 3, b = k & 7;
      wait_prog(b, (unsigned)(j * 4 + 4));
      process_group(b, j * 4, 4);
    }
  }
}

extern "C" void kernel_launch(void* const* d_in, const int* in_sizes, int n_in,
                              void* d_out, int out_size, void* d_ws, size_t ws_size,
                              hipStream_t stream) {
  (void)in_sizes; (void)n_in; (void)out_size; (void)ws_size;
  const float* xyz    = (const float*)d_in[0];
  const float* points = (const float*)d_in[1];
  const float* W0 = (const float*)d_in[2];
  const float* g0 = (const float*)d_in[3];
  const float* b0 = (const float*)d_in[4];
  const float* m0 = (const float*)d_in[5];
  const float* v0 = (const float*)d_in[6];
  const float* W1 = (const float*)d_in[7];
  const float* g1 = (const float*)d_in[8];
  const float* b1 = (const float*)d_in[9];
  const float* m1 = (const float*)d_in[10];
  const float* v1 = (const float*)d_in[11];
  const float* W2 = (const float*)d_in[12];
  const float* g2 = (const float*)d_in[13];
  const float* b2 = (const float*)d_in[14];
  const float* m2 = (const float*)d_in[15];
  const float* v2 = (const float*)d_in[16];

  float* new_xyz    = (float*)d_out;                 // 8*1024*3
  float* new_points = new_xyz + 8 * 1024 * 3;        // 8*1024*128
  float* idxf       = new_points + 8 * 1024 * 128;   // 8*1024*32

  unsigned int* prog = (unsigned int*)d_ws;          // 8 counters, 128B apart
  hipMemsetAsync(d_ws, 0, 8 * 32 * sizeof(unsigned int), stream);
  fused_kernel<<<320, 256, 0, stream>>>(xyz, points, W0, g0, b0, m0, v0,
                                        W1, g1, b1, m1, v1,
                                        W2, g2, b2, m2, v2,
                                        new_xyz, new_points, idxf, prog);
}

// Round 3
// 722.156 us; speedup vs baseline: 1.1380x; 1.0308x over previous
//
#include <hip/hip_runtime.h>
#include <stdint.h>

#define BN_EPS 0.001f

typedef float v2f __attribute__((ext_vector_type(2)));

// ---------------------------------------------------------------------------
// R12: fused producer-consumer, v3.
// R11 lesson: relaxed-atomic protocol fixed the wbl2/inv storm (outlier gone,
// -33us) but 112us remains above the 571us fps floor. Decomposition:
// (1) flush __syncthreads right after 96 sc1 stores = ~0.3-0.6us x32 of
//     whole-block vmcnt-drain stalls on the fps critical path;
// (2) final-publish cliff: centroids >=992 processed as 4-sequential-MLP
//     groups after fps ends;
// (3) ballq is a ~64-chunk serial latency chain for FPS-chosen (isolated)
//     centroids — early-exit rarely helps, loads sit on the chain.
// Fixes: (1) DEFERRED publish — at chunk cc's flush, publish cc*32 (chunk
// cc-1's data, stores drained 17.8us ago -> vmcnt(0) free), THEN issue cc's
// stores; post-flush barrier removed (flush reads are ordered by the last
// inner barrier + wave0 program order). Final publish 1024 after the loop.
// (2) last 32 centroids/batch -> 256 single-centroid tail blocks (grid 512,
// 2 blocks/CU); workers cover j<248 only. (3) ballq software-pipelined:
// prefetch chunk c+1's xyz during chunk c's ballot (identical FP per point).
// All FP math verbatim -> bit-identical outputs.
// ---------------------------------------------------------------------------

struct FpsSh {
  float px[4096], py[4096], pz[4096];
  unsigned long long wk[2][4];   // double-buffered wave winners
  int curh[32];                  // current chunk's centroid history
};

struct WrkSh {
  float W0s[67 * 64];            // 16.75 KB
  float W1s[64 * 64];            // 16 KB
  float sh[64 * 36];             // union: inT (67x34) / h1T (64x36)
  float h0T[64 * 34];            // also pmax in epilogue
  float s0c[64], t0c[64], s1c[64], t1c[64], s2c[128], t2c[128];
  float idxs[4 * 32];            // ballq results for up to 4 centroids
  float cent[4 * 3];             // centroid coords
};

union AllSh {  // 54,064 B -> 2 blocks/CU (108.5 KB <= 160 KB); grid 512 co-resident
  FpsSh f;
  WrkSh w;
};

__global__ __launch_bounds__(256) void fused_kernel(
    const float* __restrict__ xyz, const float* __restrict__ points,
    const float* __restrict__ W0, const float* __restrict__ g0,
    const float* __restrict__ b0, const float* __restrict__ m0,
    const float* __restrict__ v0, const float* __restrict__ W1,
    const float* __restrict__ g1, const float* __restrict__ b1,
    const float* __restrict__ m1, const float* __restrict__ v1,
    const float* __restrict__ W2, const float* __restrict__ g2,
    const float* __restrict__ b2, const float* __restrict__ m2,
    const float* __restrict__ v2, float* __restrict__ new_xyz,
    float* __restrict__ new_points, float* __restrict__ idxf,
    unsigned int* __restrict__ prog) {
  __shared__ __align__(16) AllSh smem;
  const int bid = blockIdx.x;
  const int t = threadIdx.x;

  if (bid < 8) {
    // ================= FPS producer (R4 inner loop, untouched) =============
#pragma clang fp contract(off)
    float* px = smem.f.px;
    float* py = smem.f.py;
    float* pz = smem.f.pz;
    int* curh = smem.f.curh;
    auto& wk = smem.f.wk;
    const int lane = t & 63, wid = t >> 6;
    const int b = bid;
    const float* X = xyz + (size_t)b * 4096 * 3;
    float* out = new_xyz + (size_t)b * 1024 * 3;
    v2f x[8], y[8], z[8], dist[8];
#pragma unroll
    for (int j = 0; j < 8; ++j) {
      const int n0 = (2 * j) * 256 + t;
      const int n1 = (2 * j + 1) * 256 + t;
      x[j].x = X[n0 * 3 + 0]; x[j].y = X[n1 * 3 + 0];
      y[j].x = X[n0 * 3 + 1]; y[j].y = X[n1 * 3 + 1];
      z[j].x = X[n0 * 3 + 2]; z[j].y = X[n1 * 3 + 2];
      px[n0] = x[j].x; py[n0] = y[j].x; pz[n0] = z[j].x;
      px[n1] = x[j].y; py[n1] = y[j].y; pz[n1] = z[j].y;
      dist[j] = (v2f){1e10f, 1e10f};
    }
    __syncthreads();
    int cur = 0;
    for (int cc = 0; cc < 32; ++cc) {
      for (int ii = 0; ii < 32; ++ii) {
        const int it = cc * 32 + ii;
        if (t == 0) curh[ii] = cur;        // LDS only: no vmcnt on the barrier
        const float cx = px[cur], cy = py[cur], cz = pz[cur];
        const v2f cxv = {cx, cx}, cyv = {cy, cy}, czv = {cz, cz};
        float bestv = -1.0f;
        int bestj = 0;
#pragma unroll
        for (int j = 0; j < 8; ++j) {
          v2f dx = x[j] - cxv, dy = y[j] - cyv, dz = z[j] - czv;
          v2f d = dx * dx + dy * dy;   // contract off: mul,mul,add — matches ref
          d = d + dz * dz;
          v2f nd = __builtin_elementwise_min(dist[j], d);
          dist[j] = nd;
          if (nd.x > bestv) { bestv = nd.x; bestj = 2 * j; }      // strict >
          if (nd.y > bestv) { bestv = nd.y; bestj = 2 * j + 1; }
        }
        const int besti = bestj * 256 + t;
        unsigned long long key =
            ((unsigned long long)__float_as_uint(bestv) << 32) | (unsigned)(~besti);
        // ---- wave64 max-reduce via DPP; result lands in lane 63 ----
#define DPP_STEP(CTRL)                                                                     \
        {                                                                                  \
          unsigned lo_ = (unsigned)key, hi_ = (unsigned)(key >> 32);                       \
          unsigned ls = (unsigned)__builtin_amdgcn_update_dpp((int)lo_, (int)lo_, CTRL, 0xf, 0xf, false); \
          unsigned hs = (unsigned)__builtin_amdgcn_update_dpp((int)hi_, (int)hi_, CTRL, 0xf, 0xf, false); \
          unsigned long long sk = ((unsigned long long)hs << 32) | ls;                     \
          if (sk > key) key = sk;                                                          \
        }
        DPP_STEP(0x111)  // row_shr:1
        DPP_STEP(0x112)  // row_shr:2
        DPP_STEP(0x114)  // row_shr:4
        DPP_STEP(0x118)  // row_shr:8
        DPP_STEP(0x142)  // row_bcast:15
        DPP_STEP(0x143)  // row_bcast:31
#undef DPP_STEP
        const unsigned whi = (unsigned)__builtin_amdgcn_readlane((int)(key >> 32), 63);
        const unsigned wlo = (unsigned)__builtin_amdgcn_readlane((int)key, 63);
        if (lane == 0) wk[it & 1][wid] = ((unsigned long long)whi << 32) | wlo;
        __syncthreads();
        const unsigned long long k0 = wk[it & 1][0], k1 = wk[it & 1][1];
        const unsigned long long k2 = wk[it & 1][2], k3 = wk[it & 1][3];
        unsigned long long b01 = (k1 > k0) ? k1 : k0;
        unsigned long long b23 = (k3 > k2) ? k3 : k2;
        unsigned long long bk = (b23 > b01) ? b23 : b01;
        cur = (int)(~(unsigned)(bk & 0xffffffffull));
      }
      // ---- chunk flush: deferred publish (prev chunk), then this chunk's
      // stores. No barrier: flush reads (curh/px) are ordered by the last
      // inner barrier; only wave0 touches them; other waves proceed.
      if (t == 0) {
        // cc-1's stores were issued ~17.8us ago -> this waitcnt is free, and
        // it architecturally orders data ahead of the publish flag.
        asm volatile("s_waitcnt vmcnt(0)" ::: "memory");
        if (cc > 0)
          __hip_atomic_store(&prog[b * 32], (unsigned)(cc * 32),
                             __ATOMIC_RELAXED, __HIP_MEMORY_SCOPE_AGENT);
      }
      if (t < 32) {
        const int c = curh[t];
        const int p = cc * 32 + t;
        __hip_atomic_store(&out[p * 3 + 0], px[c], __ATOMIC_RELAXED,
                           __HIP_MEMORY_SCOPE_AGENT);
        __hip_atomic_store(&out[p * 3 + 1], py[c], __ATOMIC_RELAXED,
                           __HIP_MEMORY_SCOPE_AGENT);
        __hip_atomic_store(&out[p * 3 + 2], pz[c], __ATOMIC_RELAXED,
                           __HIP_MEMORY_SCOPE_AGENT);
      }
    }
    // ---- final publish: one-time ~0.3us drain off the loop ----
    if (t == 0) {
      asm volatile("s_waitcnt vmcnt(0)" ::: "memory");
      __hip_atomic_store(&prog[b * 32], 1024u, __ATOMIC_RELAXED,
                         __HIP_MEMORY_SCOPE_AGENT);
    }
    return;
  }

  // ================= worker: ballq + MLP =================================
  float* W0s = smem.w.W0s;
  float* W1s = smem.w.W1s;
  float* s0c = smem.w.s0c; float* t0c = smem.w.t0c;
  float* s1c = smem.w.s1c; float* t1c = smem.w.t1c;
  float* s2c = smem.w.s2c; float* t2c = smem.w.t2c;
  for (int i = t; i < 67 * 64; i += 256) W0s[i] = W0[i];
  for (int i = t; i < 64 * 64; i += 256) W1s[i] = W1[i];
  if (t < 64) {
    float s = g0[t] * rsqrtf(v0[t] + BN_EPS); s0c[t] = s; t0c[t] = b0[t] - m0[t] * s;
    float u = g1[t] * rsqrtf(v1[t] + BN_EPS); s1c[t] = u; t1c[t] = b1[t] - m1[t] * u;
  }
  if (t < 128) {
    float s = g2[t] * rsqrtf(v2[t] + BN_EPS); s2c[t] = s; t2c[t] = b2[t] - m2[t] * s;
  }
  __syncthreads();
  const int sgrp = t & 15, dgrp = t >> 4;  // L0/L1 tiling
  const int dg2 = t & 31, sg2 = t >> 5;    // L2 tiling
  float* inT = smem.w.sh;                  // [c][s] stride 34, gather..L0
  float* h1T = smem.w.sh;                  // [d][s] stride 36, L1..L2
  float* h0T = smem.w.h0T;
  float* pmax = h0T;                       // alias (h0T dead by L2 epilogue)

  // Spin-wait on per-batch progress (relaxed agent loads: sc1, fresh, no
  // cache maintenance). s_sleep(8) ~= 0.2us wake granularity.
  auto wait_prog = [&](int b, unsigned need) {
    int guard = 0;
    while (__hip_atomic_load(&prog[b * 32], __ATOMIC_RELAXED,
                             __HIP_MEMORY_SCOPE_AGENT) < need) {
      __builtin_amdgcn_s_sleep(8);
      if (++guard > (1 << 20)) break;   // failsafe: never hang the harness
    }
  };

  // ballq + MLP for nc centroids starting at (batch b, point p0).
  auto process_group = [&](int b, int p0, int nc) {
    // ---- ball query: wave wv handles centroid p0+wv. Software-pipelined:
    // prefetch chunk c+1's xyz while ballot-compacting chunk c (FPS picks
    // isolated points -> early-exit rarely fires early; the load latency was
    // on the serial chain). FP math per point verbatim. ----
    {
#pragma clang fp contract(off)
      const int wv = t >> 6, lane = t & 63;
      if (wv < nc) {
        const int pg = b * 1024 + p0 + wv;
        const float* X = xyz + (size_t)b * 4096 * 3;
        const float cx = __hip_atomic_load(&new_xyz[pg * 3 + 0], __ATOMIC_RELAXED,
                                           __HIP_MEMORY_SCOPE_AGENT);
        const float cy = __hip_atomic_load(&new_xyz[pg * 3 + 1], __ATOMIC_RELAXED,
                                           __HIP_MEMORY_SCOPE_AGENT);
        const float cz = __hip_atomic_load(&new_xyz[pg * 3 + 2], __ATOMIC_RELAXED,
                                           __HIP_MEMORY_SCOPE_AGENT);
        const float csq = (cx * cx + cy * cy) + cz * cz;
        float* outg = idxf + (size_t)pg * 32;
        float* ol = smem.w.idxs + wv * 32;
        int total = 0;
        int first = -1;
        float xx = X[lane * 3 + 0], yy = X[lane * 3 + 1], zz = X[lane * 3 + 2];
        for (int chunk = 0; chunk < 64; ++chunk) {
          const int n = chunk * 64 + lane;
          float nx = xx, ny = yy, nz = zz;
          if (chunk < 63) {
            const float* Xn = X + (n + 64) * 3;
            nx = Xn[0]; ny = Xn[1]; nz = Xn[2];
          }
          const float sq = (xx * xx + yy * yy) + zz * zz;
          const float dot = fmaf(cz, zz, fmaf(cy, yy, cx * xx));  // gemm K-chain
          const float d2 = (csq + sq) - 2.0f * dot;
          const bool in = d2 < 0.04f;
          const unsigned long long mask = __ballot(in);
          if (first < 0 && mask != 0ull) first = chunk * 64 + __builtin_ctzll(mask);
          if (in) {
            const int pos = total + __builtin_popcountll(mask & ((1ull << lane) - 1ull));
            if (pos < 32) { outg[pos] = (float)n; ol[pos] = (float)n; }
          }
          total += __builtin_popcountll(mask);
          if (total >= 32) break;
          xx = nx; yy = ny; zz = nz;
        }
        if (total < 32 && first >= 0) {
          const int slot = total + lane;
          if (slot < 32) { outg[slot] = (float)first; ol[slot] = (float)first; }
        }
        if (lane == 0) {
          smem.w.cent[wv * 3 + 0] = cx;
          smem.w.cent[wv * 3 + 1] = cy;
          smem.w.cent[wv * 3 + 2] = cz;
        }
      }
    }
    __syncthreads();
    // ---- MLP: nc centroids sequentially (verbatim R9 math) ----
    for (int pp = 0; pp < nc; ++pp) {
      const int pg = b * 1024 + p0 + pp;
      const float cx = smem.w.cent[pp * 3 + 0];
      const float cy = smem.w.cent[pp * 3 + 1];
      const float cz = smem.w.cent[pp * 3 + 2];
      // ---- gather stage (writes inT) ----
      {
        const int s = t >> 3, cg = t & 7;
        const int i = (int)smem.w.idxs[pp * 32 + s];
        const float* Pr = points + ((size_t)b * 4096 + i) * 64 + cg * 8;
        const float4 a = *(const float4*)Pr;
        const float4 c4 = *(const float4*)(Pr + 4);
        const int r = 3 + cg * 8;
        inT[(r + 0) * 34 + s] = a.x;  inT[(r + 1) * 34 + s] = a.y;
        inT[(r + 2) * 34 + s] = a.z;  inT[(r + 3) * 34 + s] = a.w;
        inT[(r + 4) * 34 + s] = c4.x; inT[(r + 5) * 34 + s] = c4.y;
        inT[(r + 6) * 34 + s] = c4.z; inT[(r + 7) * 34 + s] = c4.w;
        if (t < 32) {
          const int i2 = (int)smem.w.idxs[pp * 32 + t];
          const float* Xr = xyz + ((size_t)b * 4096 + i2) * 3;
          inT[0 * 34 + t] = Xr[0] - cx;
          inT[1 * 34 + t] = Xr[1] - cy;
          inT[2 * 34 + t] = Xr[2] - cz;
        }
      }
      __syncthreads();
      // ---- L0: 67 -> 64 ----
      {
        float acc[2][4] = {{0, 0, 0, 0}, {0, 0, 0, 0}};
#pragma unroll 4
        for (int c = 0; c < 67; ++c) {
          const float2 a = *(const float2*)&inT[c * 34 + 2 * sgrp];
          const float4 w = *(const float4*)&W0s[c * 64 + 4 * dgrp];
          acc[0][0] = fmaf(a.x, w.x, acc[0][0]); acc[0][1] = fmaf(a.x, w.y, acc[0][1]);
          acc[0][2] = fmaf(a.x, w.z, acc[0][2]); acc[0][3] = fmaf(a.x, w.w, acc[0][3]);
          acc[1][0] = fmaf(a.y, w.x, acc[1][0]); acc[1][1] = fmaf(a.y, w.y, acc[1][1]);
          acc[1][2] = fmaf(a.y, w.z, acc[1][2]); acc[1][3] = fmaf(a.y, w.w, acc[1][3]);
        }
#pragma unroll
        for (int dj = 0; dj < 4; ++dj) {
          const int d = 4 * dgrp + dj;
          const float s = s0c[d], bb = t0c[d];
#pragma unroll
          for (int si = 0; si < 2; ++si) {
            float yv = fmaf(acc[si][dj], s, bb);
            h0T[d * 34 + 2 * sgrp + si] = fmaxf(yv, 0.0f);
          }
        }
      }
      __syncthreads();
      // ---- L1: 64 -> 64 ----
      {
        float acc[2][4] = {{0, 0, 0, 0}, {0, 0, 0, 0}};
#pragma unroll 4
        for (int c = 0; c < 64; ++c) {
          const float2 a = *(const float2*)&h0T[c * 34 + 2 * sgrp];
          const float4 w = *(const float4*)&W1s[c * 64 + 4 * dgrp];
          acc[0][0] = fmaf(a.x, w.x, acc[0][0]); acc[0][1] = fmaf(a.x, w.y, acc[0][1]);
          acc[0][2] = fmaf(a.x, w.z, acc[0][2]); acc[0][3] = fmaf(a.x, w.w, acc[0][3]);
          acc[1][0] = fmaf(a.y, w.x, acc[1][0]); acc[1][1] = fmaf(a.y, w.y, acc[1][1]);
          acc[1][2] = fmaf(a.y, w.z, acc[1][2]); acc[1][3] = fmaf(a.y, w.w, acc[1][3]);
        }
#pragma unroll
        for (int dj = 0; dj < 4; ++dj) {
          const int d = 4 * dgrp + dj;
          const float s = s1c[d], bb = t1c[d];
#pragma unroll
          for (int si = 0; si < 2; ++si) {
            float yv = fmaf(acc[si][dj], s, bb);
            h1T[d * 36 + 2 * sgrp + si] = fmaxf(yv, 0.0f);
          }
        }
      }
      __syncthreads();
      // ---- L2: 64 -> 128, fused BN+ReLU+max ----
      {
        float acc[4][4] = {{0,0,0,0},{0,0,0,0},{0,0,0,0},{0,0,0,0}};
#pragma unroll 8
        for (int c = 0; c < 64; ++c) {
          const float4 a = *(const float4*)&h1T[c * 36 + 4 * sg2];
          const float4 w = *(const float4*)(W2 + c * 128 + 4 * dg2);
          acc[0][0] = fmaf(a.x, w.x, acc[0][0]); acc[0][1] = fmaf(a.x, w.y, acc[0][1]);
          acc[0][2] = fmaf(a.x, w.z, acc[0][2]); acc[0][3] = fmaf(a.x, w.w, acc[0][3]);
          acc[1][0] = fmaf(a.y, w.x, acc[1][0]); acc[1][1] = fmaf(a.y, w.y, acc[1][1]);
          acc[1][2] = fmaf(a.y, w.z, acc[1][2]); acc[1][3] = fmaf(a.y, w.w, acc[1][3]);
          acc[2][0] = fmaf(a.z, w.x, acc[2][0]); acc[2][1] = fmaf(a.z, w.y, acc[2][1]);
          acc[2][2] = fmaf(a.z, w.z, acc[2][2]); acc[2][3] = fmaf(a.z, w.w, acc[2][3]);
          acc[3][0] = fmaf(a.w, w.x, acc[3][0]); acc[3][1] = fmaf(a.w, w.y, acc[3][1]);
          acc[3][2] = fmaf(a.w, w.z, acc[3][2]); acc[3][3] = fmaf(a.w, w.w, acc[3][3]);
        }
#pragma unroll
        for (int dj = 0; dj < 4; ++dj) {
          const int d = 4 * dg2 + dj;
          const float s = s2c[d], bb = t2c[d];
          float mx = 0.0f;  // relu outputs are >= 0
#pragma unroll
          for (int si = 0; si < 4; ++si) {
            float yv = fmaf(acc[si][dj], s, bb);
            mx = fmaxf(mx, fmaxf(yv, 0.0f));
          }
          pmax[sg2 * 128 + d] = mx;
        }
      }
      __syncthreads();
      if (t < 128) {
        float mx = pmax[t];
#pragma unroll
        for (int g = 1; g < 8; ++g) mx = fmaxf(mx, pmax[g * 128 + t]);
        new_points[(size_t)pg * 128 + t] = mx;
      }
      __syncthreads();
    }
  };

  if (bid >= 256) {
    // 256 single-centroid tail blocks: centroids 992..1023 of each batch are
    // only published at the END (deferred publish) -> one 1-centroid pipeline
    // each, fully parallel, instead of 4-sequential-MLP groups.
    const int sid = bid - 256;          // 0..255
    const int b = sid & 7;              // spread across batches
    const int p0 = 992 + (sid >> 3);    // 992..1023
    wait_prog(b, (unsigned)(p0 + 1));
    process_group(b, p0, 1);
  } else {
    // 248 normal workers: j=0..247 (centroids 0..991), ready-order k = j*8+b.
    for (int k = bid - 8; k < 1984; k += 248) {
      const int j = k >> 3, b = k & 7;
      wait_prog(b, (unsigned)(j * 4 + 4));
      process_group(b, j * 4, 4);
    }
  }
}

extern "C" void kernel_launch(void* const* d_in, const int* in_sizes, int n_in,
                              void* d_out, int out_size, void* d_ws, size_t ws_size,
                              hipStream_t stream) {
  (void)in_sizes; (void)n_in; (void)out_size; (void)ws_size;
  const float* xyz    = (const float*)d_in[0];
  const float* points = (const float*)d_in[1];
  const float* W0 = (const float*)d_in[2];
  const float* g0 = (const float*)d_in[3];
  const float* b0 = (const float*)d_in[4];
  const float* m0 = (const float*)d_in[5];
  const float* v0 = (const float*)d_in[6];
  const float* W1 = (const float*)d_in[7];
  const float* g1 = (const float*)d_in[8];
  const float* b1 = (const float*)d_in[9];
  const float* m1 = (const float*)d_in[10];
  const float* v1 = (const float*)d_in[11];
  const float* W2 = (const float*)d_in[12];
  const float* g2 = (const float*)d_in[13];
  const float* b2 = (const float*)d_in[14];
  const float* m2 = (const float*)d_in[15];
  const float* v2 = (const float*)d_in[16];

  float* new_xyz    = (float*)d_out;                 // 8*1024*3
  float* new_points = new_xyz + 8 * 1024 * 3;        // 8*1024*128
  float* idxf       = new_points + 8 * 1024 * 128;   // 8*1024*32

  unsigned int* prog = (unsigned int*)d_ws;          // 8 counters, 128B apart
  hipMemsetAsync(d_ws, 0, 8 * 32 * sizeof(unsigned int), stream);
  fused_kernel<<<512, 256, 0, stream>>>(xyz, points, W0, g0, b0, m0, v0,
                                        W1, g1, b1, m1, v1,
                                        W2, g2, b2, m2, v2,
                                        new_xyz, new_points, idxf, prog);
}

// Round 5
// 699.822 us; speedup vs baseline: 1.1743x; 1.0319x over previous
//
#include <hip/hip_runtime.h>
#include <stdint.h>

#define BN_EPS 0.001f

typedef float v2f __attribute__((ext_vector_type(2)));

// ---------------------------------------------------------------------------
// R14: R13's algorithmic wins on R12's PROVEN chassis (grid 512, 2 blocks/CU).
// R13 (grid 768 = exact 3-blocks/CU machine-fill) killed the container twice —
// can't rule out a residency/starvation hazard (spin-waiting workers filling
// all slots while fps is starved -> guard-timeout storm), so exact-fill grids
// are off the table. Kept from R13:
// (1) EARLY 992 PUBLISH at chunk 30's flush (one ~0.4us vmcnt drain, wave0
//     only) -> centroids 960..991 + all worker groups ready ~17.8us before
//     fps ends.
// (2) Workers cover j<240 only (centroids 0..959); the 256 tail blocks each
//     run TWO sequential single-centroid pipelines: (b, 960+q) at the early
//     publish (overlaps chunk 31), then (b, 992+q) at the final publish.
//     True end-phase = one 1-centroid ballq+MLP (~10us), replacing R12's
//     4-sequential-MLP end-groups.
// All FP math verbatim -> bit-identical outputs. fps inner loop untouched
// (R4 frozen). Publish-covers-data ordering preserved (every publish follows
// a vmcnt(0) covering its stores).
// ---------------------------------------------------------------------------

struct FpsSh {
  float px[4096], py[4096], pz[4096];
  unsigned long long wk[2][4];   // double-buffered wave winners
  int curh[32];                  // current chunk's centroid history
};

struct WrkSh {
  float W0s[67 * 64];            // 16.75 KB
  float W1s[64 * 64];            // 16 KB
  float sh[64 * 36];             // union: inT (67x34) / h1T (64x36)
  float h0T[64 * 34];            // also pmax in epilogue
  float s0c[64], t0c[64], s1c[64], t1c[64], s2c[128], t2c[128];
  float idxs[4 * 32];            // ballq results for up to 4 centroids
  float cent[4 * 3];             // centroid coords
};

union AllSh {  // 54,064 B -> 2 blocks/CU; grid 512 fully co-resident (proven R12)
  FpsSh f;
  WrkSh w;
};

__global__ __launch_bounds__(256) void fused_kernel(
    const float* __restrict__ xyz, const float* __restrict__ points,
    const float* __restrict__ W0, const float* __restrict__ g0,
    const float* __restrict__ b0, const float* __restrict__ m0,
    const float* __restrict__ v0, const float* __restrict__ W1,
    const float* __restrict__ g1, const float* __restrict__ b1,
    const float* __restrict__ m1, const float* __restrict__ v1,
    const float* __restrict__ W2, const float* __restrict__ g2,
    const float* __restrict__ b2, const float* __restrict__ m2,
    const float* __restrict__ v2, float* __restrict__ new_xyz,
    float* __restrict__ new_points, float* __restrict__ idxf,
    unsigned int* __restrict__ prog) {
  __shared__ __align__(16) AllSh smem;
  const int bid = blockIdx.x;
  const int t = threadIdx.x;

  if (bid < 8) {
    // ================= FPS producer (R4 inner loop, untouched) =============
#pragma clang fp contract(off)
    float* px = smem.f.px;
    float* py = smem.f.py;
    float* pz = smem.f.pz;
    int* curh = smem.f.curh;
    auto& wk = smem.f.wk;
    const int lane = t & 63, wid = t >> 6;
    const int b = bid;
    const float* X = xyz + (size_t)b * 4096 * 3;
    float* out = new_xyz + (size_t)b * 1024 * 3;
    v2f x[8], y[8], z[8], dist[8];
#pragma unroll
    for (int j = 0; j < 8; ++j) {
      const int n0 = (2 * j) * 256 + t;
      const int n1 = (2 * j + 1) * 256 + t;
      x[j].x = X[n0 * 3 + 0]; x[j].y = X[n1 * 3 + 0];
      y[j].x = X[n0 * 3 + 1]; y[j].y = X[n1 * 3 + 1];
      z[j].x = X[n0 * 3 + 2]; z[j].y = X[n1 * 3 + 2];
      px[n0] = x[j].x; py[n0] = y[j].x; pz[n0] = z[j].x;
      px[n1] = x[j].y; py[n1] = y[j].y; pz[n1] = z[j].y;
      dist[j] = (v2f){1e10f, 1e10f};
    }
    __syncthreads();
    int cur = 0;
    for (int cc = 0; cc < 32; ++cc) {
      for (int ii = 0; ii < 32; ++ii) {
        const int it = cc * 32 + ii;
        if (t == 0) curh[ii] = cur;        // LDS only: no vmcnt on the barrier
        const float cx = px[cur], cy = py[cur], cz = pz[cur];
        const v2f cxv = {cx, cx}, cyv = {cy, cy}, czv = {cz, cz};
        float bestv = -1.0f;
        int bestj = 0;
#pragma unroll
        for (int j = 0; j < 8; ++j) {
          v2f dx = x[j] - cxv, dy = y[j] - cyv, dz = z[j] - czv;
          v2f d = dx * dx + dy * dy;   // contract off: mul,mul,add — matches ref
          d = d + dz * dz;
          v2f nd = __builtin_elementwise_min(dist[j], d);
          dist[j] = nd;
          if (nd.x > bestv) { bestv = nd.x; bestj = 2 * j; }      // strict >
          if (nd.y > bestv) { bestv = nd.y; bestj = 2 * j + 1; }
        }
        const int besti = bestj * 256 + t;
        unsigned long long key =
            ((unsigned long long)__float_as_uint(bestv) << 32) | (unsigned)(~besti);
        // ---- wave64 max-reduce via DPP; result lands in lane 63 ----
#define DPP_STEP(CTRL)                                                                     \
        {                                                                                  \
          unsigned lo_ = (unsigned)key, hi_ = (unsigned)(key >> 32);                       \
          unsigned ls = (unsigned)__builtin_amdgcn_update_dpp((int)lo_, (int)lo_, CTRL, 0xf, 0xf, false); \
          unsigned hs = (unsigned)__builtin_amdgcn_update_dpp((int)hi_, (int)hi_, CTRL, 0xf, 0xf, false); \
          unsigned long long sk = ((unsigned long long)hs << 32) | ls;                     \
          if (sk > key) key = sk;                                                          \
        }
        DPP_STEP(0x111)  // row_shr:1
        DPP_STEP(0x112)  // row_shr:2
        DPP_STEP(0x114)  // row_shr:4
        DPP_STEP(0x118)  // row_shr:8
        DPP_STEP(0x142)  // row_bcast:15
        DPP_STEP(0x143)  // row_bcast:31
#undef DPP_STEP
        const unsigned whi = (unsigned)__builtin_amdgcn_readlane((int)(key >> 32), 63);
        const unsigned wlo = (unsigned)__builtin_amdgcn_readlane((int)key, 63);
        if (lane == 0) wk[it & 1][wid] = ((unsigned long long)whi << 32) | wlo;
        __syncthreads();
        const unsigned long long k0 = wk[it & 1][0], k1 = wk[it & 1][1];
        const unsigned long long k2 = wk[it & 1][2], k3 = wk[it & 1][3];
        unsigned long long b01 = (k1 > k0) ? k1 : k0;
        unsigned long long b23 = (k3 > k2) ? k3 : k2;
        unsigned long long bk = (b23 > b01) ? b23 : b01;
        cur = (int)(~(unsigned)(bk & 0xffffffffull));
      }
      // ---- chunk flush: deferred publish (prev chunk), then this chunk's
      // stores. No barrier: flush reads (curh/px) are ordered by the last
      // inner barrier; only wave0 touches them; other waves proceed.
      if (t == 0) {
        // cc-1's stores were issued ~17.8us ago -> this waitcnt is free, and
        // it architecturally orders data ahead of the publish flag.
        asm volatile("s_waitcnt vmcnt(0)" ::: "memory");
        if (cc > 0)
          __hip_atomic_store(&prog[b * 32], (unsigned)(cc * 32),
                             __ATOMIC_RELAXED, __HIP_MEMORY_SCOPE_AGENT);
      }
      if (t < 32) {
        const int c = curh[t];
        const int p = cc * 32 + t;
        __hip_atomic_store(&out[p * 3 + 0], px[c], __ATOMIC_RELAXED,
                           __HIP_MEMORY_SCOPE_AGENT);
        __hip_atomic_store(&out[p * 3 + 1], py[c], __ATOMIC_RELAXED,
                           __HIP_MEMORY_SCOPE_AGENT);
        __hip_atomic_store(&out[p * 3 + 2], pz[c], __ATOMIC_RELAXED,
                           __HIP_MEMORY_SCOPE_AGENT);
      }
      // ---- EARLY 992 PUBLISH: chunk 30's stores just issued; drain them
      // (~0.4us, wave0 only, once) and publish so centroids 960..991 and all
      // remaining worker groups run DURING chunk 31 instead of after fps.
      if (cc == 30 && t == 0) {
        asm volatile("s_waitcnt vmcnt(0)" ::: "memory");
        __hip_atomic_store(&prog[b * 32], 992u, __ATOMIC_RELAXED,
                           __HIP_MEMORY_SCOPE_AGENT);
      }
    }
    // ---- final publish: one-time ~0.3us drain off the loop ----
    if (t == 0) {
      asm volatile("s_waitcnt vmcnt(0)" ::: "memory");
      __hip_atomic_store(&prog[b * 32], 1024u, __ATOMIC_RELAXED,
                         __HIP_MEMORY_SCOPE_AGENT);
    }
    return;
  }

  // ================= worker: ballq + MLP =================================
  float* W0s = smem.w.W0s;
  float* W1s = smem.w.W1s;
  float* s0c = smem.w.s0c; float* t0c = smem.w.t0c;
  float* s1c = smem.w.s1c; float* t1c = smem.w.t1c;
  float* s2c = smem.w.s2c; float* t2c = smem.w.t2c;
  for (int i = t; i < 67 * 64; i += 256) W0s[i] = W0[i];
  for (int i = t; i < 64 * 64; i += 256) W1s[i] = W1[i];
  if (t < 64) {
    float s = g0[t] * rsqrtf(v0[t] + BN_EPS); s0c[t] = s; t0c[t] = b0[t] - m0[t] * s;
    float u = g1[t] * rsqrtf(v1[t] + BN_EPS); s1c[t] = u; t1c[t] = b1[t] - m1[t] * u;
  }
  if (t < 128) {
    float s = g2[t] * rsqrtf(v2[t] + BN_EPS); s2c[t] = s; t2c[t] = b2[t] - m2[t] * s;
  }
  __syncthreads();
  const int sgrp = t & 15, dgrp = t >> 4;  // L0/L1 tiling
  const int dg2 = t & 31, sg2 = t >> 5;    // L2 tiling
  float* inT = smem.w.sh;                  // [c][s] stride 34, gather..L0
  float* h1T = smem.w.sh;                  // [d][s] stride 36, L1..L2
  float* h0T = smem.w.h0T;
  float* pmax = h0T;                       // alias (h0T dead by L2 epilogue)

  // Spin-wait on per-batch progress (relaxed agent loads: sc1, fresh, no
  // cache maintenance). s_sleep(8) ~= 0.2us wake granularity.
  auto wait_prog = [&](int b, unsigned need) {
    int guard = 0;
    while (__hip_atomic_load(&prog[b * 32], __ATOMIC_RELAXED,
                             __HIP_MEMORY_SCOPE_AGENT) < need) {
      __builtin_amdgcn_s_sleep(8);
      if (++guard > (1 << 20)) break;   // failsafe: never hang the harness
    }
  };

  // ballq + MLP for nc centroids starting at (batch b, point p0).
  auto process_group = [&](int b, int p0, int nc) {
    // ---- ball query: wave wv handles centroid p0+wv. Software-pipelined:
    // prefetch chunk c+1's xyz while ballot-compacting chunk c (FPS picks
    // isolated points -> early-exit rarely fires early; the load latency was
    // on the serial chain). FP math per point verbatim. ----
    {
#pragma clang fp contract(off)
      const int wv = t >> 6, lane = t & 63;
      if (wv < nc) {
        const int pg = b * 1024 + p0 + wv;
        const float* X = xyz + (size_t)b * 4096 * 3;
        const float cx = __hip_atomic_load(&new_xyz[pg * 3 + 0], __ATOMIC_RELAXED,
                                           __HIP_MEMORY_SCOPE_AGENT);
        const float cy = __hip_atomic_load(&new_xyz[pg * 3 + 1], __ATOMIC_RELAXED,
                                           __HIP_MEMORY_SCOPE_AGENT);
        const float cz = __hip_atomic_load(&new_xyz[pg * 3 + 2], __ATOMIC_RELAXED,
                                           __HIP_MEMORY_SCOPE_AGENT);
        const float csq = (cx * cx + cy * cy) + cz * cz;
        float* outg = idxf + (size_t)pg * 32;
        float* ol = smem.w.idxs + wv * 32;
        int total = 0;
        int first = -1;
        float xx = X[lane * 3 + 0], yy = X[lane * 3 + 1], zz = X[lane * 3 + 2];
        for (int chunk = 0; chunk < 64; ++chunk) {
          const int n = chunk * 64 + lane;
          float nx = xx, ny = yy, nz = zz;
          if (chunk < 63) {
            const float* Xn = X + (n + 64) * 3;
            nx = Xn[0]; ny = Xn[1]; nz = Xn[2];
          }
          const float sq = (xx * xx + yy * yy) + zz * zz;
          const float dot = fmaf(cz, zz, fmaf(cy, yy, cx * xx));  // gemm K-chain
          const float d2 = (csq + sq) - 2.0f * dot;
          const bool in = d2 < 0.04f;
          const unsigned long long mask = __ballot(in);
          if (first < 0 && mask != 0ull) first = chunk * 64 + __builtin_ctzll(mask);
          if (in) {
            const int pos = total + __builtin_popcountll(mask & ((1ull << lane) - 1ull));
            if (pos < 32) { outg[pos] = (float)n; ol[pos] = (float)n; }
          }
          total += __builtin_popcountll(mask);
          if (total >= 32) break;
          xx = nx; yy = ny; zz = nz;
        }
        if (total < 32 && first >= 0) {
          const int slot = total + lane;
          if (slot < 32) { outg[slot] = (float)first; ol[slot] = (float)first; }
        }
        if (lane == 0) {
          smem.w.cent[wv * 3 + 0] = cx;
          smem.w.cent[wv * 3 + 1] = cy;
          smem.w.cent[wv * 3 + 2] = cz;
        }
      }
    }
    __syncthreads();
    // ---- MLP: nc centroids sequentially (verbatim R9 math) ----
    for (int pp = 0; pp < nc; ++pp) {
      const int pg = b * 1024 + p0 + pp;
      const float cx = smem.w.cent[pp * 3 + 0];
      const float cy = smem.w.cent[pp * 3 + 1];
      const float cz = smem.w.cent[pp * 3 + 2];
      // ---- gather stage (writes inT) ----
      {
        const int s = t >> 3, cg = t & 7;
        const int i = (int)smem.w.idxs[pp * 32 + s];
        const float* Pr = points + ((size_t)b * 4096 + i) * 64 + cg * 8;
        const float4 a = *(const float4*)Pr;
        const float4 c4 = *(const float4*)(Pr + 4);
        const int r = 3 + cg * 8;
        inT[(r + 0) * 34 + s] = a.x;  inT[(r + 1) * 34 + s] = a.y;
        inT[(r + 2) * 34 + s] = a.z;  inT[(r + 3) * 34 + s] = a.w;
        inT[(r + 4) * 34 + s] = c4.x; inT[(r + 5) * 34 + s] = c4.y;
        inT[(r + 6) * 34 + s] = c4.z; inT[(r + 7) * 34 + s] = c4.w;
        if (t < 32) {
          const int i2 = (int)smem.w.idxs[pp * 32 + t];
          const float* Xr = xyz + ((size_t)b * 4096 + i2) * 3;
          inT[0 * 34 + t] = Xr[0] - cx;
          inT[1 * 34 + t] = Xr[1] - cy;
          inT[2 * 34 + t] = Xr[2] - cz;
        }
      }
      __syncthreads();
      // ---- L0: 67 -> 64 ----
      {
        float acc[2][4] = {{0, 0, 0, 0}, {0, 0, 0, 0}};
#pragma unroll 4
        for (int c = 0; c < 67; ++c) {
          const float2 a = *(const float2*)&inT[c * 34 + 2 * sgrp];
          const float4 w = *(const float4*)&W0s[c * 64 + 4 * dgrp];
          acc[0][0] = fmaf(a.x, w.x, acc[0][0]); acc[0][1] = fmaf(a.x, w.y, acc[0][1]);
          acc[0][2] = fmaf(a.x, w.z, acc[0][2]); acc[0][3] = fmaf(a.x, w.w, acc[0][3]);
          acc[1][0] = fmaf(a.y, w.x, acc[1][0]); acc[1][1] = fmaf(a.y, w.y, acc[1][1]);
          acc[1][2] = fmaf(a.y, w.z, acc[1][2]); acc[1][3] = fmaf(a.y, w.w, acc[1][3]);
        }
#pragma unroll
        for (int dj = 0; dj < 4; ++dj) {
          const int d = 4 * dgrp + dj;
          const float s = s0c[d], bb = t0c[d];
#pragma unroll
          for (int si = 0; si < 2; ++si) {
            float yv = fmaf(acc[si][dj], s, bb);
            h0T[d * 34 + 2 * sgrp + si] = fmaxf(yv, 0.0f);
          }
        }
      }
      __syncthreads();
      // ---- L1: 64 -> 64 ----
      {
        float acc[2][4] = {{0, 0, 0, 0}, {0, 0, 0, 0}};
#pragma unroll 4
        for (int c = 0; c < 64; ++c) {
          const float2 a = *(const float2*)&h0T[c * 34 + 2 * sgrp];
          const float4 w = *(const float4*)&W1s[c * 64 + 4 * dgrp];
          acc[0][0] = fmaf(a.x, w.x, acc[0][0]); acc[0][1] = fmaf(a.x, w.y, acc[0][1]);
          acc[0][2] = fmaf(a.x, w.z, acc[0][2]); acc[0][3] = fmaf(a.x, w.w, acc[0][3]);
          acc[1][0] = fmaf(a.y, w.x, acc[1][0]); acc[1][1] = fmaf(a.y, w.y, acc[1][1]);
          acc[1][2] = fmaf(a.y, w.z, acc[1][2]); acc[1][3] = fmaf(a.y, w.w, acc[1][3]);
        }
#pragma unroll
        for (int dj = 0; dj < 4; ++dj) {
          const int d = 4 * dgrp + dj;
          const float s = s1c[d], bb = t1c[d];
#pragma unroll
          for (int si = 0; si < 2; ++si) {
            float yv = fmaf(acc[si][dj], s, bb);
            h1T[d * 36 + 2 * sgrp + si] = fmaxf(yv, 0.0f);
          }
        }
      }
      __syncthreads();
      // ---- L2: 64 -> 128, fused BN+ReLU+max ----
      {
        float acc[4][4] = {{0,0,0,0},{0,0,0,0},{0,0,0,0},{0,0,0,0}};
#pragma unroll 8
        for (int c = 0; c < 64; ++c) {
          const float4 a = *(const float4*)&h1T[c * 36 + 4 * sg2];
          const float4 w = *(const float4*)(W2 + c * 128 + 4 * dg2);
          acc[0][0] = fmaf(a.x, w.x, acc[0][0]); acc[0][1] = fmaf(a.x, w.y, acc[0][1]);
          acc[0][2] = fmaf(a.x, w.z, acc[0][2]); acc[0][3] = fmaf(a.x, w.w, acc[0][3]);
          acc[1][0] = fmaf(a.y, w.x, acc[1][0]); acc[1][1] = fmaf(a.y, w.y, acc[1][1]);
          acc[1][2] = fmaf(a.y, w.z, acc[1][2]); acc[1][3] = fmaf(a.y, w.w, acc[1][3]);
          acc[2][0] = fmaf(a.z, w.x, acc[2][0]); acc[2][1] = fmaf(a.z, w.y, acc[2][1]);
          acc[2][2] = fmaf(a.z, w.z, acc[2][2]); acc[2][3] = fmaf(a.z, w.w, acc[2][3]);
          acc[3][0] = fmaf(a.w, w.x, acc[3][0]); acc[3][1] = fmaf(a.w, w.y, acc[3][1]);
          acc[3][2] = fmaf(a.w, w.z, acc[3][2]); acc[3][3] = fmaf(a.w, w.w, acc[3][3]);
        }
#pragma unroll
        for (int dj = 0; dj < 4; ++dj) {
          const int d = 4 * dg2 + dj;
          const float s = s2c[d], bb = t2c[d];
          float mx = 0.0f;  // relu outputs are >= 0
#pragma unroll
          for (int si = 0; si < 4; ++si) {
            float yv = fmaf(acc[si][dj], s, bb);
            mx = fmaxf(mx, fmaxf(yv, 0.0f));
          }
          pmax[sg2 * 128 + d] = mx;
        }
      }
      __syncthreads();
      if (t < 128) {
        float mx = pmax[t];
#pragma unroll
        for (int g = 1; g < 8; ++g) mx = fmaxf(mx, pmax[g * 128 + t]);
        new_points[(size_t)pg * 128 + t] = mx;
      }
      __syncthreads();
    }
  };

  if (bid >= 256) {
    // 256 tail blocks, TWO sequential single-centroid pipelines each:
    // first (b, 960+q) — ready at the early-992 publish, overlaps chunk 31;
    // then (b, 992+q) — ready at the final publish (true end-phase ~10us).
    const int sid = bid - 256;          // 0..255
    const int b = sid & 7;              // spread across batches/XCDs
    const int q = sid >> 3;             // 0..31
    wait_prog(b, (unsigned)(960 + q + 1));
    process_group(b, 960 + q, 1);
    wait_prog(b, (unsigned)(992 + q + 1));
    process_group(b, 992 + q, 1);
  } else {
    // 248 normal workers: j=0..239 (centroids 0..959), ready-order k = j*8+b.
    for (int k = bid - 8; k < 1920; k += 248) {
      const int j = k >> 3, b = k & 7;
      wait_prog(b, (unsigned)(j * 4 + 4));
      process_group(b, j * 4, 4);
    }
  }
}

extern "C" void kernel_launch(void* const* d_in, const int* in_sizes, int n_in,
                              void* d_out, int out_size, void* d_ws, size_t ws_size,
                              hipStream_t stream) {
  (void)in_sizes; (void)n_in; (void)out_size; (void)ws_size;
  const float* xyz    = (const float*)d_in[0];
  const float* points = (const float*)d_in[1];
  const float* W0 = (const float*)d_in[2];
  const float* g0 = (const float*)d_in[3];
  const float* b0 = (const float*)d_in[4];
  const float* m0 = (const float*)d_in[5];
  const float* v0 = (const float*)d_in[6];
  const float* W1 = (const float*)d_in[7];
  const float* g1 = (const float*)d_in[8];
  const float* b1 = (const float*)d_in[9];
  const float* m1 = (const float*)d_in[10];
  const float* v1 = (const float*)d_in[11];
  const float* W2 = (const float*)d_in[12];
  const float* g2 = (const float*)d_in[13];
  const float* b2 = (const float*)d_in[14];
  const float* m2 = (const float*)d_in[15];
  const float* v2 = (const float*)d_in[16];

  float* new_xyz    = (float*)d_out;                 // 8*1024*3
  float* new_points = new_xyz + 8 * 1024 * 3;        // 8*1024*128
  float* idxf       = new_points + 8 * 1024 * 128;   // 8*1024*32

  unsigned int* prog = (unsigned int*)d_ws;          // 8 counters, 128B apart
  hipMemsetAsync(d_ws, 0, 8 * 32 * sizeof(unsigned int), stream);
  fused_kernel<<<512, 256, 0, stream>>>(xyz, points, W0, g0, b0, m0, v0,
                                        W1, g1, b1, m1, v1,
                                        W2, g2, b2, m2, v2,
                                        new_xyz, new_points, idxf, prog);
}